// Round 8
// baseline (105.752 us; speedup 1.0000x reference)
//
#include <hip/hip_runtime.h>
#include <cstdint>

#define P_N 65536
#define G_N 2048
#define L2E 1.4426950408889634f
#define NGROUP (P_N / 256)     // 256 groups of 256 sorted points
#define CHUNK 128              // records staged per LDS chunk

#if __has_builtin(__builtin_amdgcn_exp2f)
#define EXP2F __builtin_amdgcn_exp2f
#else
#define EXP2F exp2f
#endif

// ---- ws layout (units: floats/ints, 4B each) ----
#define OFF_FLAG 0
#define OFF_PAR  64
#define OFF_MU   (OFF_PAR + (G_N + 2) * 16)        // float4 (mu.xyz, r2) per g
#define OFF_HIST (OFF_MU + G_N * 4)                // 512 cell counts
#define OFF_OFFS (OFF_HIST + 512)                  // 512 cursors
#define OFF_XS   (OFF_OFFS + 512)                  // P_N float4 (X,Y,Z,idx)
#define NEED_FLOATS (OFF_XS + P_N * 4)             // ~1.22 MB

__device__ __forceinline__ float sigmoidf(float x) {
    return 1.0f / (1.0f + expf(-x));
}

__device__ __forceinline__ int morton3(int x, int y, int z) {
    int m = 0;
#pragma unroll
    for (int b = 0; b < 3; ++b)
        m |= (((x >> b) & 1) << (3 * b)) | (((y >> b) & 1) << (3 * b + 1)) |
             (((z >> b) & 1) << (3 * b + 2));
    return m;
}

// params: [0..8] M = sqrt(L2E/2)*diag(1/s)*R^T, [9..11] nb=-M·mu, [12] lw, pad
__global__ __launch_bounds__(256) void precompute_kernel(
        const float* __restrict__ xyz,
        const float* __restrict__ weight,
        const float* __restrict__ scaling,
        const float* __restrict__ rotation,
        const float* __restrict__ values,
        const uint8_t* __restrict__ inside_raw,
        float* __restrict__ ws, int aux) {
    if (blockIdx.x == 0) {
        __shared__ int s_nz;
        if (threadIdx.x == 0) s_nz = 0;
        __syncthreads();
        int nz = 0;
        for (int i = threadIdx.x; i < 4096; i += blockDim.x) {
            if ((i & 3) != 0 && inside_raw[i] != 0) nz = 1;
        }
        if (nz) atomicOr(&s_nz, 1);
        __syncthreads();
        if (threadIdx.x == 0) ((int*)ws)[OFF_FLAG] = s_nz;
        if (threadIdx.x < 32) ws[OFF_PAR + (size_t)G_N * 16 + threadIdx.x] = 0.0f;
        // zero the cell histogram (hist_kernel runs after us in stream order)
        ((int*)ws)[OFF_HIST + threadIdx.x] = 0;
        ((int*)ws)[OFF_HIST + 256 + threadIdx.x] = 0;
    }

    int g = blockIdx.x * blockDim.x + threadIdx.x;
    if (g >= G_N) return;

    float s0 = expf(scaling[3 * g + 0]);
    float s1 = expf(scaling[3 * g + 1]);
    float s2 = expf(scaling[3 * g + 2]);
    float r = sqrtf(s0 * s0 + s1 * s1 + s2 * s2) + 1e-8f;
    float r_soft = 0.02f * tanhf(r / 0.02f);
    float f = r_soft / r;
    s0 *= f; s1 *= f; s2 *= f;

    float qw = rotation[4 * g + 0], qx = rotation[4 * g + 1];
    float qy = rotation[4 * g + 2], qz = rotation[4 * g + 3];
    float qn = sqrtf(qw * qw + qx * qx + qy * qy + qz * qz) + 1e-12f;
    qw /= qn; qx /= qn; qy /= qn; qz /= qn;
    float r00 = 1.0f - 2.0f * (qy * qy + qz * qz);
    float r01 = 2.0f * (qx * qy - qw * qz);
    float r02 = 2.0f * (qx * qz + qw * qy);
    float r10 = 2.0f * (qx * qy + qw * qz);
    float r11 = 1.0f - 2.0f * (qx * qx + qz * qz);
    float r12 = 2.0f * (qy * qz - qw * qx);
    float r20 = 2.0f * (qx * qz - qw * qy);
    float r21 = 2.0f * (qy * qz + qw * qx);
    float r22 = 1.0f - 2.0f * (qx * qx + qy * qy);

    const float k = 0.84932180028801904f;  // sqrt(L2E*0.5)
    float k0 = k / s0, k1 = k / s1, k2 = k / s2;
    float m00 = k0 * r00, m01 = k0 * r10, m02 = k0 * r20;
    float m10 = k1 * r01, m11 = k1 * r11, m12 = k1 * r21;
    float m20 = k2 * r02, m21 = k2 * r12, m22 = k2 * r22;

    float mx = xyz[3 * g + 0], my = xyz[3 * g + 1], mz = xyz[3 * g + 2];
    float wv = sigmoidf(weight[g]) * sigmoidf(values[g]);

    float* c = ws + OFF_PAR + (size_t)g * 16;
    c[0] = m00; c[1] = m01; c[2] = m02;
    c[3] = m10; c[4] = m11; c[5] = m12;
    c[6] = m20; c[7] = m21; c[8] = m22;
    c[9]  = -(m00 * mx + m01 * my + m02 * mz);
    c[10] = -(m10 * mx + m11 * my + m12 * mz);
    c[11] = -(m20 * mx + m21 * my + m22 * mz);
    c[12] = log2f(wv);
    c[13] = 0.0f; c[14] = 0.0f; c[15] = 0.0f;

    if (aux) {
        // keep iff dist2(mu, bbox) < 63*smax^2  (term bound 2^-45)
        float smax = fmaxf(s0, fmaxf(s1, s2));
        ((float4*)(ws + OFF_MU))[g] = make_float4(mx, my, mz, 63.0f * smax * smax);
    }
}

__global__ __launch_bounds__(256) void hist_kernel(
        const float* __restrict__ x, float* __restrict__ ws) {
    int p = blockIdx.x * 256 + threadIdx.x;
    float X = (x[3 * p + 0] + 1.0f) * 0.5f;
    float Y = (x[3 * p + 1] + 1.0f) * 0.5f;
    float Z = (x[3 * p + 2] + 1.0f) * 0.5f;
    int cx = min(7, max(0, (int)(X * 8.0f)));
    int cy = min(7, max(0, (int)(Y * 8.0f)));
    int cz = min(7, max(0, (int)(Z * 8.0f)));
    atomicAdd(&((int*)ws)[OFF_HIST + morton3(cx, cy, cz)], 1);
}

__global__ __launch_bounds__(512) void scan_kernel(float* __restrict__ ws) {
    __shared__ int tmp[512];
    int t = threadIdx.x;
    int v = ((int*)ws)[OFF_HIST + t];
    tmp[t] = v;
    __syncthreads();
    for (int d = 1; d < 512; d <<= 1) {
        int add = (t >= d) ? tmp[t - d] : 0;
        __syncthreads();
        tmp[t] += add;
        __syncthreads();
    }
    ((int*)ws)[OFF_OFFS + t] = tmp[t] - v;  // exclusive
}

__global__ __launch_bounds__(256) void scatter_kernel(
        const float* __restrict__ x, float* __restrict__ ws) {
    int p = blockIdx.x * 256 + threadIdx.x;
    float X = (x[3 * p + 0] + 1.0f) * 0.5f;
    float Y = (x[3 * p + 1] + 1.0f) * 0.5f;
    float Z = (x[3 * p + 2] + 1.0f) * 0.5f;
    int cx = min(7, max(0, (int)(X * 8.0f)));
    int cy = min(7, max(0, (int)(Y * 8.0f)));
    int cz = min(7, max(0, (int)(Z * 8.0f)));
    int pos = atomicAdd(&((int*)ws)[OFF_OFFS + morton3(cx, cy, cz)], 1);
    ((float4*)(ws + OFF_XS))[pos] = make_float4(X, Y, Z, __int_as_float(p));
}

// one block per 256-point group: bbox -> LDS active list -> chunked eval,
// single plain store per point (no atomics, no pre-zeroed output needed)
__global__ __launch_bounds__(512) void eval_cull_kernel(
        const float* __restrict__ ws,
        const void* __restrict__ inside,
        float* __restrict__ out) {
    __shared__ int   slist[G_N];          // 8 KB active list
    __shared__ float4 sbuf[CHUNK * 4];    // 8 KB staged records
    __shared__ float  bb[6][4];           // per-wave bbox partials (waves 0-3)
    __shared__ float  comb[256];
    __shared__ int    scnt;

    const int mode = ((const int*)ws)[OFF_FLAG];
    const int b  = blockIdx.x;
    const int t  = threadIdx.x;
    const int pi = t & 255;               // point slot
    const int h  = t >> 8;                // list-parity half

    float4 pt = ((const float4*)(ws + OFF_XS))[b * 256 + pi];
    float X = pt.x, Y = pt.y, Z = pt.z;

    if (t == 0) scnt = 0;
    // bbox reduce over the 256 points (threads 0..255 = 4 waves)
    if (h == 0) {
        float mnx = X, mxx = X, mny = Y, mxy = Y, mnz = Z, mxz = Z;
        for (int d = 32; d; d >>= 1) {
            mnx = fminf(mnx, __shfl_xor(mnx, d)); mxx = fmaxf(mxx, __shfl_xor(mxx, d));
            mny = fminf(mny, __shfl_xor(mny, d)); mxy = fmaxf(mxy, __shfl_xor(mxy, d));
            mnz = fminf(mnz, __shfl_xor(mnz, d)); mxz = fmaxf(mxz, __shfl_xor(mxz, d));
        }
        int w = t >> 6;
        if ((t & 63) == 0) {
            bb[0][w] = mnx; bb[1][w] = mxx; bb[2][w] = mny;
            bb[3][w] = mxy; bb[4][w] = mnz; bb[5][w] = mxz;
        }
    }
    __syncthreads();
    float bnx = fminf(fminf(bb[0][0], bb[0][1]), fminf(bb[0][2], bb[0][3]));
    float bxx = fmaxf(fmaxf(bb[1][0], bb[1][1]), fmaxf(bb[1][2], bb[1][3]));
    float bny = fminf(fminf(bb[2][0], bb[2][1]), fminf(bb[2][2], bb[2][3]));
    float bxy = fmaxf(fmaxf(bb[3][0], bb[3][1]), fmaxf(bb[3][2], bb[3][3]));
    float bnz = fminf(fminf(bb[4][0], bb[4][1]), fminf(bb[4][2], bb[4][3]));
    float bxz = fmaxf(fmaxf(bb[5][0], bb[5][1]), fmaxf(bb[5][2], bb[5][3]));

    // active-list build: each thread tests 4 gaussians
    const float4* mu4 = (const float4*)(ws + OFF_MU);
#pragma unroll
    for (int i = 0; i < G_N / 512; ++i) {
        int g = t + 512 * i;
        float4 m = mu4[g];
        float dx = fmaxf(fmaxf(bnx - m.x, m.x - bxx), 0.0f);
        float dy = fmaxf(fmaxf(bny - m.y, m.y - bxy), 0.0f);
        float dz = fmaxf(fmaxf(bnz - m.z, m.z - bxz), 0.0f);
        float d2 = dx * dx + dy * dy + dz * dz;
        if (d2 < m.w) slist[atomicAdd(&scnt, 1)] = g;
    }
    __syncthreads();
    const int cnt = scnt;
    const float4* par4 = (const float4*)(ws + OFF_PAR);
    float acc = 0.0f;

    for (int c0 = 0; c0 < cnt; c0 += CHUNK) {
        int cn = min(CHUNK, cnt - c0);
        __syncthreads();
        for (int idx = t; idx < cn * 4; idx += 512) {
            int g = slist[c0 + (idx >> 2)];
            sbuf[idx] = par4[(size_t)g * 4 + (idx & 3)];
        }
        __syncthreads();
        for (int j = h; j < cn; j += 2) {
            float4 r0 = sbuf[j * 4 + 0], r1 = sbuf[j * 4 + 1];
            float4 r2 = sbuf[j * 4 + 2], r3 = sbuf[j * 4 + 3];
            float u0 = fmaf(r0.x, X, fmaf(r0.y, Y, fmaf(r0.z, Z, r2.y)));
            float u1 = fmaf(r0.w, X, fmaf(r1.x, Y, fmaf(r1.y, Z, r2.z)));
            float u2 = fmaf(r1.z, X, fmaf(r1.w, Y, fmaf(r2.x, Z, r2.w)));
            float tt = fmaf(-u0, u0, r3.x);
            tt = fmaf(-u1, u1, tt);
            tt = fmaf(-u2, u2, tt);
            acc += EXP2F(tt);
        }
    }

    __syncthreads();
    if (h == 1) comb[pi] = acc;
    __syncthreads();
    if (h == 0) {
        float y = acc + comb[pi];
        int p = __float_as_int(pt.w);
        bool m = mode ? (((const uint8_t*)inside)[p] != 0)
                      : (((const int*)inside)[p] != 0);
        out[p] = m ? y : 0.0f;      // every point stored exactly once
    }
}

// ---------- fallback for small ws (no memset: zero kernel + round-6 path) ----------
__global__ __launch_bounds__(256) void zero_out_kernel(float* __restrict__ out) {
    out[blockIdx.x * 256 + threadIdx.x] = 0.0f;
}

#define GAUSS_POINT(r0, r1, r2, r3, Xk, Yk, Zk, acck)                         \
    {                                                                         \
        float u0 = fmaf(r0.x, Xk, fmaf(r0.y, Yk, fmaf(r0.z, Zk, r2.y)));      \
        float u1 = fmaf(r0.w, Xk, fmaf(r1.x, Yk, fmaf(r1.y, Zk, r2.z)));      \
        float u2 = fmaf(r1.z, Xk, fmaf(r1.w, Yk, fmaf(r2.x, Zk, r2.w)));      \
        float tq = fmaf(-u0, u0, r3.x);                                       \
        tq = fmaf(-u1, u1, tq);                                               \
        tq = fmaf(-u2, u2, tq);                                               \
        acck += EXP2F(tq);                                                    \
    }
#define GAUSS_REC4(r0, r1, r2, r3)                                            \
    GAUSS_POINT(r0, r1, r2, r3, X0, Y0, Z0, acc0);                            \
    GAUSS_POINT(r0, r1, r2, r3, X1, Y1, Z1, acc1);                            \
    GAUSS_POINT(r0, r1, r2, r3, X2, Y2, Z2, acc2);                            \
    GAUSS_POINT(r0, r1, r2, r3, X3, Y3, Z3, acc3);

__global__ __launch_bounds__(256) void eval_kernel(
        const float* __restrict__ x,
        const float* __restrict__ ws,
        const void* __restrict__ inside,
        float* __restrict__ out) {
    __shared__ float4 spbuf[1028];
    const float* params = ws + OFF_PAR;
    const int mode = ((const int*)ws)[OFF_FLAG];
    const int tid = threadIdx.x, lane = tid & 63, w = tid >> 6;
    const int segq = blockIdx.x & 7, pg = blockIdx.x >> 3;

    const float4* src = (const float4*)(params + (size_t)segq * 256 * 16);
#pragma unroll
    for (int i = 0; i < 4; ++i) spbuf[tid + 256 * i] = src[tid + 256 * i];
    if (tid < 4) spbuf[1024 + tid] = src[1024 + tid];

    const int p0 = pg * 256 + lane;
    float X0 = (x[3 * (p0 + 0) + 0] + 1.0f) * 0.5f;
    float Y0 = (x[3 * (p0 + 0) + 1] + 1.0f) * 0.5f;
    float Z0 = (x[3 * (p0 + 0) + 2] + 1.0f) * 0.5f;
    float X1 = (x[3 * (p0 + 64) + 0] + 1.0f) * 0.5f;
    float Y1 = (x[3 * (p0 + 64) + 1] + 1.0f) * 0.5f;
    float Z1 = (x[3 * (p0 + 64) + 2] + 1.0f) * 0.5f;
    float X2 = (x[3 * (p0 + 128) + 0] + 1.0f) * 0.5f;
    float Y2 = (x[3 * (p0 + 128) + 1] + 1.0f) * 0.5f;
    float Z2 = (x[3 * (p0 + 128) + 2] + 1.0f) * 0.5f;
    float X3 = (x[3 * (p0 + 192) + 0] + 1.0f) * 0.5f;
    float Y3 = (x[3 * (p0 + 192) + 1] + 1.0f) * 0.5f;
    float Z3 = (x[3 * (p0 + 192) + 2] + 1.0f) * 0.5f;
    __syncthreads();

    const float4* sp = spbuf + (size_t)w * 256;
    float acc0 = 0, acc1 = 0, acc2 = 0, acc3 = 0;
    float4 A0 = sp[0], A1 = sp[1], A2 = sp[2], A3 = sp[3];
    float4 B0, B1, B2, B3;
#pragma unroll 1
    for (int g = 0; g < 64; g += 2) {
        const float4* q = sp + (size_t)(g + 1) * 4;
        B0 = q[0]; B1 = q[1]; B2 = q[2]; B3 = q[3];
        GAUSS_REC4(A0, A1, A2, A3);
        q = sp + (size_t)(g + 2) * 4;
        A0 = q[0]; A1 = q[1]; A2 = q[2]; A3 = q[3];
        GAUSS_REC4(B0, B1, B2, B3);
    }
    __syncthreads();
    float* part = (float*)spbuf;
    part[w * 256 + 0 + lane] = acc0;
    part[w * 256 + 64 + lane] = acc1;
    part[w * 256 + 128 + lane] = acc2;
    part[w * 256 + 192 + lane] = acc3;
    __syncthreads();
    float y = part[tid] + part[256 + tid] + part[512 + tid] + part[768 + tid];
    int p = pg * 256 + tid;
    bool m = mode ? (((const uint8_t*)inside)[p] != 0)
                  : (((const int*)inside)[p] != 0);
    if (m) atomicAdd(&out[p], y);
}

extern "C" void kernel_launch(void* const* d_in, const int* in_sizes, int n_in,
                              void* d_out, int out_size, void* d_ws, size_t ws_size,
                              hipStream_t stream) {
    const float* x        = (const float*)d_in[0];
    const float* xyz      = (const float*)d_in[1];
    const float* weight   = (const float*)d_in[2];
    const float* scaling  = (const float*)d_in[3];
    const float* rotation = (const float*)d_in[4];
    const float* values   = (const float*)d_in[5];
    const void*  inside   = d_in[6];

    float* ws = (float*)d_ws;

    if (ws_size >= (size_t)NEED_FLOATS * 4) {
        precompute_kernel<<<(G_N + 255) / 256, 256, 0, stream>>>(
            xyz, weight, scaling, rotation, values, (const uint8_t*)inside, ws, 1);
        hist_kernel<<<P_N / 256, 256, 0, stream>>>(x, ws);
        scan_kernel<<<1, 512, 0, stream>>>(ws);
        scatter_kernel<<<P_N / 256, 256, 0, stream>>>(x, ws);
        eval_cull_kernel<<<NGROUP, 512, 0, stream>>>(ws, inside, (float*)d_out);
    } else if (ws_size >= (size_t)(256 + (G_N + 2) * 16 * 4)) {
        zero_out_kernel<<<P_N / 256, 256, 0, stream>>>((float*)d_out);
        precompute_kernel<<<(G_N + 255) / 256, 256, 0, stream>>>(
            xyz, weight, scaling, rotation, values, (const uint8_t*)inside, ws, 0);
        eval_kernel<<<(P_N / 256) * 8, 256, 0, stream>>>(
            x, ws, inside, (float*)d_out);
    }
}

// Round 9
// 40.692 us; speedup vs baseline: 2.5988x; 2.5988x over previous
//
#include <hip/hip_runtime.h>
#include <cstdint>

#define P_N 65536
#define G_N 2048
#define L2E 1.4426950408889634f
#define NCELL 512              // 8x8x8 grid
#define BCAP 320               // bucket capacity (mean 128, sd ~11 -> 17 sigma)
#define CHUNK 128              // records staged per LDS chunk

#if __has_builtin(__builtin_amdgcn_exp2f)
#define EXP2F __builtin_amdgcn_exp2f
#else
#define EXP2F exp2f
#endif

// ---- ws layout (units: floats/ints, 4B each) ----
#define OFF_FLAG 0
#define OFF_PAR  64
#define OFF_MU   (OFF_PAR + (G_N + 2) * 16)   // 32864: float4 (mu.xyz, r2)
#define OFF_CNT  (OFF_MU + G_N * 4)           // 41056: 512 cell counts
#define OFF_BKT  (OFF_CNT + NCELL)            // 41568: 512*BCAP float4 (X,Y,Z,idx)
#define NEED_FLOATS (OFF_BKT + NCELL * BCAP * 4)   // ~2.79 MB

__device__ __forceinline__ float sigmoidf(float x) {
    return 1.0f / (1.0f + expf(-x));
}

// params: [0..8] M = sqrt(L2E/2)*diag(1/s)*R^T, [9..11] nb=-M·mu, [12] lw, pad
__global__ __launch_bounds__(256) void precompute_kernel(
        const float* __restrict__ xyz,
        const float* __restrict__ weight,
        const float* __restrict__ scaling,
        const float* __restrict__ rotation,
        const float* __restrict__ values,
        const uint8_t* __restrict__ inside_raw,
        float* __restrict__ ws, int aux) {
    if (blockIdx.x == 0) {
        __shared__ int s_nz;
        if (threadIdx.x == 0) s_nz = 0;
        __syncthreads();
        int nz = 0;
        for (int i = threadIdx.x; i < 4096; i += blockDim.x) {
            if ((i & 3) != 0 && inside_raw[i] != 0) nz = 1;
        }
        if (nz) atomicOr(&s_nz, 1);
        __syncthreads();
        if (threadIdx.x == 0) ((int*)ws)[OFF_FLAG] = s_nz;
        if (threadIdx.x < 32) ws[OFF_PAR + (size_t)G_N * 16 + threadIdx.x] = 0.0f;
        // zero bucket counters (scatter_kernel runs in a later dispatch)
        ((int*)ws)[OFF_CNT + threadIdx.x] = 0;
        ((int*)ws)[OFF_CNT + 256 + threadIdx.x] = 0;
    }

    int g = blockIdx.x * blockDim.x + threadIdx.x;
    if (g >= G_N) return;

    float s0 = expf(scaling[3 * g + 0]);
    float s1 = expf(scaling[3 * g + 1]);
    float s2 = expf(scaling[3 * g + 2]);
    float r = sqrtf(s0 * s0 + s1 * s1 + s2 * s2) + 1e-8f;
    float r_soft = 0.02f * tanhf(r / 0.02f);
    float f = r_soft / r;
    s0 *= f; s1 *= f; s2 *= f;

    float qw = rotation[4 * g + 0], qx = rotation[4 * g + 1];
    float qy = rotation[4 * g + 2], qz = rotation[4 * g + 3];
    float qn = sqrtf(qw * qw + qx * qx + qy * qy + qz * qz) + 1e-12f;
    qw /= qn; qx /= qn; qy /= qn; qz /= qn;
    float r00 = 1.0f - 2.0f * (qy * qy + qz * qz);
    float r01 = 2.0f * (qx * qy - qw * qz);
    float r02 = 2.0f * (qx * qz + qw * qy);
    float r10 = 2.0f * (qx * qy + qw * qz);
    float r11 = 1.0f - 2.0f * (qx * qx + qz * qz);
    float r12 = 2.0f * (qy * qz - qw * qx);
    float r20 = 2.0f * (qx * qz - qw * qy);
    float r21 = 2.0f * (qy * qz + qw * qx);
    float r22 = 1.0f - 2.0f * (qx * qx + qy * qy);

    const float k = 0.84932180028801904f;  // sqrt(L2E*0.5)
    float k0 = k / s0, k1 = k / s1, k2 = k / s2;
    float m00 = k0 * r00, m01 = k0 * r10, m02 = k0 * r20;
    float m10 = k1 * r01, m11 = k1 * r11, m12 = k1 * r21;
    float m20 = k2 * r02, m21 = k2 * r12, m22 = k2 * r22;

    float mx = xyz[3 * g + 0], my = xyz[3 * g + 1], mz = xyz[3 * g + 2];
    float wv = sigmoidf(weight[g]) * sigmoidf(values[g]);

    float* c = ws + OFF_PAR + (size_t)g * 16;
    c[0] = m00; c[1] = m01; c[2] = m02;
    c[3] = m10; c[4] = m11; c[5] = m12;
    c[6] = m20; c[7] = m21; c[8] = m22;
    c[9]  = -(m00 * mx + m01 * my + m02 * mz);
    c[10] = -(m10 * mx + m11 * my + m12 * mz);
    c[11] = -(m20 * mx + m21 * my + m22 * mz);
    c[12] = log2f(wv);
    c[13] = 0.0f; c[14] = 0.0f; c[15] = 0.0f;

    if (aux) {
        // keep iff dist2(mu, cellbox) < 40*smax^2
        // dropped term <= 2^(-0.7213*40) = 2^-28.8; x2048 ~= 4e-6 total
        float smax = fmaxf(s0, fmaxf(s1, s2));
        ((float4*)(ws + OFF_MU))[g] = make_float4(mx, my, mz, 40.0f * smax * smax);
    }
}

__global__ __launch_bounds__(256) void scatter_kernel(
        const float* __restrict__ x, float* __restrict__ ws) {
    int p = blockIdx.x * 256 + threadIdx.x;
    float X = (x[3 * p + 0] + 1.0f) * 0.5f;
    float Y = (x[3 * p + 1] + 1.0f) * 0.5f;
    float Z = (x[3 * p + 2] + 1.0f) * 0.5f;
    int cx = min(7, max(0, (int)(X * 8.0f)));
    int cy = min(7, max(0, (int)(Y * 8.0f)));
    int cz = min(7, max(0, (int)(Z * 8.0f)));
    int c = cx + 8 * cy + 64 * cz;
    int pos = atomicAdd(&((int*)ws)[OFF_CNT + c], 1);
    if (pos < BCAP)
        ((float4*)(ws + OFF_BKT))[(size_t)c * BCAP + pos] =
            make_float4(X, Y, Z, __int_as_float(p));
}

// one block per cell: analytic cell bounds -> LDS active list -> chunked eval
// single plain store per point (buckets partition points; no atomics/zeroing)
__global__ __launch_bounds__(512) void eval_cell_kernel(
        const float* __restrict__ ws,
        const void* __restrict__ inside,
        float* __restrict__ out) {
    __shared__ int    slist[G_N];         // 8 KB active list
    __shared__ float4 sbuf[CHUNK * 4];    // 8 KB staged records
    __shared__ float  comb[3][128];
    __shared__ int    scnt;

    const int mode = ((const int*)ws)[OFF_FLAG];
    const int c = blockIdx.x;
    const int t = threadIdx.x;
    const int pi = t & 127;               // point slot
    const int h  = t >> 7;                // record-quarter 0..3

    const int cx = c & 7, cy = (c >> 3) & 7, cz = c >> 6;
    const float bnx = cx * 0.125f, bxx = bnx + 0.125f;
    const float bny = cy * 0.125f, bxy = bny + 0.125f;
    const float bnz = cz * 0.125f, bxz = bnz + 0.125f;

    int npts = ((const int*)ws)[OFF_CNT + c];
    npts = min(npts, BCAP);

    if (t == 0) scnt = 0;
    __syncthreads();

    // active-list build: each thread tests 4 gaussians vs the cell box
    const float4* mu4 = (const float4*)(ws + OFF_MU);
#pragma unroll
    for (int i = 0; i < G_N / 512; ++i) {
        int g = t + 512 * i;
        float4 m = mu4[g];
        float dx = fmaxf(fmaxf(bnx - m.x, m.x - bxx), 0.0f);
        float dy = fmaxf(fmaxf(bny - m.y, m.y - bxy), 0.0f);
        float dz = fmaxf(fmaxf(bnz - m.z, m.z - bxz), 0.0f);
        float d2 = dx * dx + dy * dy + dz * dz;
        if (d2 < m.w) slist[atomicAdd(&scnt, 1)] = g;
    }
    __syncthreads();
    const int cnt = scnt;
    const float4* par4 = (const float4*)(ws + OFF_PAR);
    const float4* bkt  = (const float4*)(ws + OFF_BKT) + (size_t)c * BCAP;

#define EVAL_REC(J, ACC)                                                      \
    {                                                                         \
        float4 r0 = sbuf[(J) * 4 + 0], r1 = sbuf[(J) * 4 + 1];                \
        float4 r2 = sbuf[(J) * 4 + 2], r3 = sbuf[(J) * 4 + 3];                \
        float u0 = fmaf(r0.x, X, fmaf(r0.y, Y, fmaf(r0.z, Z, r2.y)));         \
        float u1 = fmaf(r0.w, X, fmaf(r1.x, Y, fmaf(r1.y, Z, r2.z)));         \
        float u2 = fmaf(r1.z, X, fmaf(r1.w, Y, fmaf(r2.x, Z, r2.w)));         \
        float tt = fmaf(-u0, u0, r3.x);                                       \
        tt = fmaf(-u1, u1, tt);                                               \
        tt = fmaf(-u2, u2, tt);                                               \
        ACC += EXP2F(tt);                                                     \
    }

    for (int base = 0; base < npts; base += 128) {
        int myp = base + pi;
        float4 pt = bkt[myp < npts ? myp : (npts - 1)];
        float X = pt.x, Y = pt.y, Z = pt.z;
        float acc0 = 0.0f, acc1 = 0.0f;

        for (int c0 = 0; c0 < cnt; c0 += CHUNK) {
            int cn = min(CHUNK, cnt - c0);
            __syncthreads();
            for (int idx = t; idx < cn * 4; idx += 512) {
                int g = slist[c0 + (idx >> 2)];
                sbuf[idx] = par4[(size_t)g * 4 + (idx & 3)];
            }
            __syncthreads();
            int j = h;
            for (; j + 4 < cn; j += 8) { EVAL_REC(j, acc0); EVAL_REC(j + 4, acc1); }
            for (; j < cn; j += 4) EVAL_REC(j, acc0);
        }
        float acc = acc0 + acc1;

        __syncthreads();
        if (h) comb[h - 1][pi] = acc;
        __syncthreads();
        if (h == 0 && myp < npts) {
            float y = acc + comb[0][pi] + comb[1][pi] + comb[2][pi];
            int p = __float_as_int(pt.w);
            bool m = mode ? (((const uint8_t*)inside)[p] != 0)
                          : (((const int*)inside)[p] != 0);
            out[p] = m ? y : 0.0f;
        }
        __syncthreads();
    }
#undef EVAL_REC
}

// ---------- fallback for small ws (round-6 path) ----------
__global__ __launch_bounds__(256) void zero_out_kernel(float* __restrict__ out) {
    out[blockIdx.x * 256 + threadIdx.x] = 0.0f;
}

#define GAUSS_POINT(r0, r1, r2, r3, Xk, Yk, Zk, acck)                         \
    {                                                                         \
        float u0 = fmaf(r0.x, Xk, fmaf(r0.y, Yk, fmaf(r0.z, Zk, r2.y)));      \
        float u1 = fmaf(r0.w, Xk, fmaf(r1.x, Yk, fmaf(r1.y, Zk, r2.z)));      \
        float u2 = fmaf(r1.z, Xk, fmaf(r1.w, Yk, fmaf(r2.x, Zk, r2.w)));      \
        float tq = fmaf(-u0, u0, r3.x);                                       \
        tq = fmaf(-u1, u1, tq);                                               \
        tq = fmaf(-u2, u2, tq);                                               \
        acck += EXP2F(tq);                                                    \
    }
#define GAUSS_REC4(r0, r1, r2, r3)                                            \
    GAUSS_POINT(r0, r1, r2, r3, X0, Y0, Z0, acc0);                            \
    GAUSS_POINT(r0, r1, r2, r3, X1, Y1, Z1, acc1);                            \
    GAUSS_POINT(r0, r1, r2, r3, X2, Y2, Z2, acc2);                            \
    GAUSS_POINT(r0, r1, r2, r3, X3, Y3, Z3, acc3);

__global__ __launch_bounds__(256) void eval_kernel(
        const float* __restrict__ x,
        const float* __restrict__ ws,
        const void* __restrict__ inside,
        float* __restrict__ out) {
    __shared__ float4 spbuf[1028];
    const float* params = ws + OFF_PAR;
    const int mode = ((const int*)ws)[OFF_FLAG];
    const int tid = threadIdx.x, lane = tid & 63, w = tid >> 6;
    const int segq = blockIdx.x & 7, pg = blockIdx.x >> 3;

    const float4* src = (const float4*)(params + (size_t)segq * 256 * 16);
#pragma unroll
    for (int i = 0; i < 4; ++i) spbuf[tid + 256 * i] = src[tid + 256 * i];
    if (tid < 4) spbuf[1024 + tid] = src[1024 + tid];

    const int p0 = pg * 256 + lane;
    float X0 = (x[3 * (p0 + 0) + 0] + 1.0f) * 0.5f;
    float Y0 = (x[3 * (p0 + 0) + 1] + 1.0f) * 0.5f;
    float Z0 = (x[3 * (p0 + 0) + 2] + 1.0f) * 0.5f;
    float X1 = (x[3 * (p0 + 64) + 0] + 1.0f) * 0.5f;
    float Y1 = (x[3 * (p0 + 64) + 1] + 1.0f) * 0.5f;
    float Z1 = (x[3 * (p0 + 64) + 2] + 1.0f) * 0.5f;
    float X2 = (x[3 * (p0 + 128) + 0] + 1.0f) * 0.5f;
    float Y2 = (x[3 * (p0 + 128) + 1] + 1.0f) * 0.5f;
    float Z2 = (x[3 * (p0 + 128) + 2] + 1.0f) * 0.5f;
    float X3 = (x[3 * (p0 + 192) + 0] + 1.0f) * 0.5f;
    float Y3 = (x[3 * (p0 + 192) + 1] + 1.0f) * 0.5f;
    float Z3 = (x[3 * (p0 + 192) + 2] + 1.0f) * 0.5f;
    __syncthreads();

    const float4* sp = spbuf + (size_t)w * 256;
    float acc0 = 0, acc1 = 0, acc2 = 0, acc3 = 0;
    float4 A0 = sp[0], A1 = sp[1], A2 = sp[2], A3 = sp[3];
    float4 B0, B1, B2, B3;
#pragma unroll 1
    for (int g = 0; g < 64; g += 2) {
        const float4* q = sp + (size_t)(g + 1) * 4;
        B0 = q[0]; B1 = q[1]; B2 = q[2]; B3 = q[3];
        GAUSS_REC4(A0, A1, A2, A3);
        q = sp + (size_t)(g + 2) * 4;
        A0 = q[0]; A1 = q[1]; A2 = q[2]; A3 = q[3];
        GAUSS_REC4(B0, B1, B2, B3);
    }
    __syncthreads();
    float* part = (float*)spbuf;
    part[w * 256 + 0 + lane] = acc0;
    part[w * 256 + 64 + lane] = acc1;
    part[w * 256 + 128 + lane] = acc2;
    part[w * 256 + 192 + lane] = acc3;
    __syncthreads();
    float y = part[tid] + part[256 + tid] + part[512 + tid] + part[768 + tid];
    int p = pg * 256 + tid;
    bool m = mode ? (((const uint8_t*)inside)[p] != 0)
                  : (((const int*)inside)[p] != 0);
    if (m) atomicAdd(&out[p], y);
}

extern "C" void kernel_launch(void* const* d_in, const int* in_sizes, int n_in,
                              void* d_out, int out_size, void* d_ws, size_t ws_size,
                              hipStream_t stream) {
    const float* x        = (const float*)d_in[0];
    const float* xyz      = (const float*)d_in[1];
    const float* weight   = (const float*)d_in[2];
    const float* scaling  = (const float*)d_in[3];
    const float* rotation = (const float*)d_in[4];
    const float* values   = (const float*)d_in[5];
    const void*  inside   = d_in[6];

    float* ws = (float*)d_ws;

    if (ws_size >= (size_t)NEED_FLOATS * 4) {
        precompute_kernel<<<(G_N + 255) / 256, 256, 0, stream>>>(
            xyz, weight, scaling, rotation, values, (const uint8_t*)inside, ws, 1);
        scatter_kernel<<<P_N / 256, 256, 0, stream>>>(x, ws);
        eval_cell_kernel<<<NCELL, 512, 0, stream>>>(ws, inside, (float*)d_out);
    } else if (ws_size >= (size_t)(256 + (G_N + 2) * 16 * 4)) {
        zero_out_kernel<<<P_N / 256, 256, 0, stream>>>((float*)d_out);
        precompute_kernel<<<(G_N + 255) / 256, 256, 0, stream>>>(
            xyz, weight, scaling, rotation, values, (const uint8_t*)inside, ws, 0);
        eval_kernel<<<(P_N / 256) * 8, 256, 0, stream>>>(
            x, ws, inside, (float*)d_out);
    }
}

// Round 10
// 40.375 us; speedup vs baseline: 2.6192x; 1.0079x over previous
//
#include <hip/hip_runtime.h>
#include <cstdint>

#define P_N 65536
#define G_N 2048
#define L2E 1.4426950408889634f
#define NCELL 512              // 8x8x8 grid
#define BCAP 320               // bucket capacity (mean 128, sd ~11 -> 17 sigma)
#define CHUNK 128              // records staged per LDS chunk

#if __has_builtin(__builtin_amdgcn_exp2f)
#define EXP2F __builtin_amdgcn_exp2f
#else
#define EXP2F exp2f
#endif

// ---- ws layout (units: floats/ints, 4B each) ----
#define OFF_FLAG 0
#define OFF_PAR  64
#define OFF_MU   (OFF_PAR + (G_N + 2) * 16)   // float4 (mu.xyz, r2)
#define OFF_CNT  (OFF_MU + G_N * 4)           // 512 cell counts
#define OFF_BKT  (OFF_CNT + NCELL)            // 512*BCAP float4 (X,Y,Z,idx)
#define NEED_FLOATS (OFF_BKT + NCELL * BCAP * 4)   // ~2.79 MB

__device__ __forceinline__ float sigmoidf(float x) {
    return 1.0f / (1.0f + expf(-x));
}

// params: [0..8] M = sqrt(L2E/2)*diag(1/s)*R^T, [9..11] nb=-M·mu, [12] lw, pad
__global__ __launch_bounds__(256) void precompute_kernel(
        const float* __restrict__ xyz,
        const float* __restrict__ weight,
        const float* __restrict__ scaling,
        const float* __restrict__ rotation,
        const float* __restrict__ values,
        const uint8_t* __restrict__ inside_raw,
        float* __restrict__ ws, int aux) {
    if (blockIdx.x == 0) {
        __shared__ int s_nz;
        if (threadIdx.x == 0) s_nz = 0;
        __syncthreads();
        int nz = 0;
        for (int i = threadIdx.x; i < 4096; i += blockDim.x) {
            if ((i & 3) != 0 && inside_raw[i] != 0) nz = 1;
        }
        if (nz) atomicOr(&s_nz, 1);
        __syncthreads();
        if (threadIdx.x == 0) ((int*)ws)[OFF_FLAG] = s_nz;
        if (threadIdx.x < 32) ws[OFF_PAR + (size_t)G_N * 16 + threadIdx.x] = 0.0f;
        // zero bucket counters (scatter_kernel runs in a later dispatch)
        ((int*)ws)[OFF_CNT + threadIdx.x] = 0;
        ((int*)ws)[OFF_CNT + 256 + threadIdx.x] = 0;
    }

    int g = blockIdx.x * blockDim.x + threadIdx.x;
    if (g >= G_N) return;

    float s0 = expf(scaling[3 * g + 0]);
    float s1 = expf(scaling[3 * g + 1]);
    float s2 = expf(scaling[3 * g + 2]);
    float r = sqrtf(s0 * s0 + s1 * s1 + s2 * s2) + 1e-8f;
    float r_soft = 0.02f * tanhf(r / 0.02f);
    float f = r_soft / r;
    s0 *= f; s1 *= f; s2 *= f;

    float qw = rotation[4 * g + 0], qx = rotation[4 * g + 1];
    float qy = rotation[4 * g + 2], qz = rotation[4 * g + 3];
    float qn = sqrtf(qw * qw + qx * qx + qy * qy + qz * qz) + 1e-12f;
    qw /= qn; qx /= qn; qy /= qn; qz /= qn;
    float r00 = 1.0f - 2.0f * (qy * qy + qz * qz);
    float r01 = 2.0f * (qx * qy - qw * qz);
    float r02 = 2.0f * (qx * qz + qw * qy);
    float r10 = 2.0f * (qx * qy + qw * qz);
    float r11 = 1.0f - 2.0f * (qx * qx + qz * qz);
    float r12 = 2.0f * (qy * qz - qw * qx);
    float r20 = 2.0f * (qx * qz - qw * qy);
    float r21 = 2.0f * (qy * qz + qw * qx);
    float r22 = 1.0f - 2.0f * (qx * qx + qy * qy);

    const float k = 0.84932180028801904f;  // sqrt(L2E*0.5)
    float k0 = k / s0, k1 = k / s1, k2 = k / s2;
    float m00 = k0 * r00, m01 = k0 * r10, m02 = k0 * r20;
    float m10 = k1 * r01, m11 = k1 * r11, m12 = k1 * r21;
    float m20 = k2 * r02, m21 = k2 * r12, m22 = k2 * r22;

    float mx = xyz[3 * g + 0], my = xyz[3 * g + 1], mz = xyz[3 * g + 2];
    float wv = sigmoidf(weight[g]) * sigmoidf(values[g]);

    float* c = ws + OFF_PAR + (size_t)g * 16;
    c[0] = m00; c[1] = m01; c[2] = m02;
    c[3] = m10; c[4] = m11; c[5] = m12;
    c[6] = m20; c[7] = m21; c[8] = m22;
    c[9]  = -(m00 * mx + m01 * my + m02 * mz);
    c[10] = -(m10 * mx + m11 * my + m12 * mz);
    c[11] = -(m20 * mx + m21 * my + m22 * mz);
    c[12] = log2f(wv);
    c[13] = 0.0f; c[14] = 0.0f; c[15] = 0.0f;

    if (aux) {
        // keep iff dist2(mu, cellbox) < 40*smax^2
        // dropped term <= 2^(-0.7213*40) = 2^-28.8; x2048 ~= 4e-6 total
        float smax = fmaxf(s0, fmaxf(s1, s2));
        ((float4*)(ws + OFF_MU))[g] = make_float4(mx, my, mz, 40.0f * smax * smax);
    }
}

__global__ __launch_bounds__(256) void scatter_kernel(
        const float* __restrict__ x, float* __restrict__ ws) {
    int p = blockIdx.x * 256 + threadIdx.x;
    float X = (x[3 * p + 0] + 1.0f) * 0.5f;
    float Y = (x[3 * p + 1] + 1.0f) * 0.5f;
    float Z = (x[3 * p + 2] + 1.0f) * 0.5f;
    int cx = min(7, max(0, (int)(X * 8.0f)));
    int cy = min(7, max(0, (int)(Y * 8.0f)));
    int cz = min(7, max(0, (int)(Z * 8.0f)));
    int c = cx + 8 * cy + 64 * cz;
    int pos = atomicAdd(&((int*)ws)[OFF_CNT + c], 1);
    if (pos < BCAP)
        ((float4*)(ws + OFF_BKT))[(size_t)c * BCAP + pos] =
            make_float4(X, Y, Z, __int_as_float(p));
}

// one block per cell: analytic bounds -> ballot-compacted LDS active list ->
// chunked eval; single plain store per point (buckets partition the points)
__global__ __launch_bounds__(512) void eval_cell_kernel(
        const float* __restrict__ ws,
        const void* __restrict__ inside,
        float* __restrict__ out) {
    __shared__ int    slist[G_N];         // 8 KB active list
    __shared__ float4 sbuf[CHUNK * 4];    // 8 KB staged records
    __shared__ float  comb[256];
    __shared__ int    scnt;

    const int mode = ((const int*)ws)[OFF_FLAG];
    const int c = blockIdx.x;
    const int t = threadIdx.x;
    const int lane = t & 63;
    const int pi = t & 255;               // point slot
    const int h  = t >> 8;                // record-parity half (0/1)

    const int cx = c & 7, cy = (c >> 3) & 7, cz = c >> 6;
    const float bnx = cx * 0.125f, bxx = bnx + 0.125f;
    const float bny = cy * 0.125f, bxy = bny + 0.125f;
    const float bnz = cz * 0.125f, bxz = bnz + 0.125f;

    int npts = ((const int*)ws)[OFF_CNT + c];
    npts = min(npts, BCAP);

    if (t == 0) scnt = 0;
    __syncthreads();

    // ballot-compacted list build: 1 LDS atomic per wave per round
    const float4* mu4 = (const float4*)(ws + OFF_MU);
    const unsigned long long lmask = (lane == 63) ? ~0ull : ((1ull << (lane + 1)) - 1ull);
#pragma unroll
    for (int i = 0; i < G_N / 512; ++i) {
        int g = t + 512 * i;
        float4 m = mu4[g];
        float dx = fmaxf(fmaxf(bnx - m.x, m.x - bxx), 0.0f);
        float dy = fmaxf(fmaxf(bny - m.y, m.y - bxy), 0.0f);
        float dz = fmaxf(fmaxf(bnz - m.z, m.z - bxz), 0.0f);
        float d2 = dx * dx + dy * dy + dz * dz;
        bool keep = d2 < m.w;
        unsigned long long mask = __ballot(keep);
        int nk = __popcll(mask);
        int pref = __popcll(mask & lmask) - (keep ? 1 : 0);  // lanes below me
        int base = 0;
        if (lane == 0) base = atomicAdd(&scnt, nk);
        base = __shfl(base, 0);
        if (keep) slist[base + pref] = g;
    }
    __syncthreads();
    const int cnt = scnt;
    const float4* par4 = (const float4*)(ws + OFF_PAR);
    const float4* bkt  = (const float4*)(ws + OFF_BKT) + (size_t)c * BCAP;

#define EVAL_REC(J, ACC)                                                      \
    {                                                                         \
        float4 r0 = sbuf[(J) * 4 + 0], r1 = sbuf[(J) * 4 + 1];                \
        float4 r2 = sbuf[(J) * 4 + 2], r3 = sbuf[(J) * 4 + 3];                \
        float u0 = fmaf(r0.x, X, fmaf(r0.y, Y, fmaf(r0.z, Z, r2.y)));         \
        float u1 = fmaf(r0.w, X, fmaf(r1.x, Y, fmaf(r1.y, Z, r2.z)));         \
        float u2 = fmaf(r1.z, X, fmaf(r1.w, Y, fmaf(r2.x, Z, r2.w)));         \
        float tt = fmaf(-u0, u0, r3.x);                                       \
        tt = fmaf(-u1, u1, tt);                                               \
        tt = fmaf(-u2, u2, tt);                                               \
        ACC += EXP2F(tt);                                                     \
    }

    // 256-point batches (most cells: exactly one), 2-way record split
    for (int base = 0; base < npts; base += 256) {
        int myp = base + pi;
        bool valid = myp < npts;
        float4 pt = bkt[valid ? myp : (npts - 1)];
        float X = pt.x, Y = pt.y, Z = pt.z;
        float acc0 = 0.0f, acc1 = 0.0f;

        for (int c0 = 0; c0 < cnt; c0 += CHUNK) {
            int cn = min(CHUNK, cnt - c0);
            __syncthreads();
            for (int idx = t; idx < cn * 4; idx += 512) {
                int g = slist[c0 + (idx >> 2)];
                sbuf[idx] = par4[(size_t)g * 4 + (idx & 3)];
            }
            __syncthreads();
            int j = h;
            for (; j + 2 < cn; j += 4) { EVAL_REC(j, acc0); EVAL_REC(j + 2, acc1); }
            for (; j < cn; j += 2) EVAL_REC(j, acc0);
        }
        float acc = acc0 + acc1;

        __syncthreads();
        if (h == 1) comb[pi] = acc;
        __syncthreads();
        if (h == 0 && valid) {
            float y = acc + comb[pi];
            int p = __float_as_int(pt.w);
            bool m = mode ? (((const uint8_t*)inside)[p] != 0)
                          : (((const int*)inside)[p] != 0);
            out[p] = m ? y : 0.0f;
        }
    }
#undef EVAL_REC
}

// ---------- fallback for small ws (round-6 path) ----------
__global__ __launch_bounds__(256) void zero_out_kernel(float* __restrict__ out) {
    out[blockIdx.x * 256 + threadIdx.x] = 0.0f;
}

#define GAUSS_POINT(r0, r1, r2, r3, Xk, Yk, Zk, acck)                         \
    {                                                                         \
        float u0 = fmaf(r0.x, Xk, fmaf(r0.y, Yk, fmaf(r0.z, Zk, r2.y)));      \
        float u1 = fmaf(r0.w, Xk, fmaf(r1.x, Yk, fmaf(r1.y, Zk, r2.z)));      \
        float u2 = fmaf(r1.z, Xk, fmaf(r1.w, Yk, fmaf(r2.x, Zk, r2.w)));      \
        float tq = fmaf(-u0, u0, r3.x);                                       \
        tq = fmaf(-u1, u1, tq);                                               \
        tq = fmaf(-u2, u2, tq);                                               \
        acck += EXP2F(tq);                                                    \
    }
#define GAUSS_REC4(r0, r1, r2, r3)                                            \
    GAUSS_POINT(r0, r1, r2, r3, X0, Y0, Z0, acc0);                            \
    GAUSS_POINT(r0, r1, r2, r3, X1, Y1, Z1, acc1);                            \
    GAUSS_POINT(r0, r1, r2, r3, X2, Y2, Z2, acc2);                            \
    GAUSS_POINT(r0, r1, r2, r3, X3, Y3, Z3, acc3);

__global__ __launch_bounds__(256) void eval_kernel(
        const float* __restrict__ x,
        const float* __restrict__ ws,
        const void* __restrict__ inside,
        float* __restrict__ out) {
    __shared__ float4 spbuf[1028];
    const float* params = ws + OFF_PAR;
    const int mode = ((const int*)ws)[OFF_FLAG];
    const int tid = threadIdx.x, lane = tid & 63, w = tid >> 6;
    const int segq = blockIdx.x & 7, pg = blockIdx.x >> 3;

    const float4* src = (const float4*)(params + (size_t)segq * 256 * 16);
#pragma unroll
    for (int i = 0; i < 4; ++i) spbuf[tid + 256 * i] = src[tid + 256 * i];
    if (tid < 4) spbuf[1024 + tid] = src[1024 + tid];

    const int p0 = pg * 256 + lane;
    float X0 = (x[3 * (p0 + 0) + 0] + 1.0f) * 0.5f;
    float Y0 = (x[3 * (p0 + 0) + 1] + 1.0f) * 0.5f;
    float Z0 = (x[3 * (p0 + 0) + 2] + 1.0f) * 0.5f;
    float X1 = (x[3 * (p0 + 64) + 0] + 1.0f) * 0.5f;
    float Y1 = (x[3 * (p0 + 64) + 1] + 1.0f) * 0.5f;
    float Z1 = (x[3 * (p0 + 64) + 2] + 1.0f) * 0.5f;
    float X2 = (x[3 * (p0 + 128) + 0] + 1.0f) * 0.5f;
    float Y2 = (x[3 * (p0 + 128) + 1] + 1.0f) * 0.5f;
    float Z2 = (x[3 * (p0 + 128) + 2] + 1.0f) * 0.5f;
    float X3 = (x[3 * (p0 + 192) + 0] + 1.0f) * 0.5f;
    float Y3 = (x[3 * (p0 + 192) + 1] + 1.0f) * 0.5f;
    float Z3 = (x[3 * (p0 + 192) + 2] + 1.0f) * 0.5f;
    __syncthreads();

    const float4* sp = spbuf + (size_t)w * 256;
    float acc0 = 0, acc1 = 0, acc2 = 0, acc3 = 0;
    float4 A0 = sp[0], A1 = sp[1], A2 = sp[2], A3 = sp[3];
    float4 B0, B1, B2, B3;
#pragma unroll 1
    for (int g = 0; g < 64; g += 2) {
        const float4* q = sp + (size_t)(g + 1) * 4;
        B0 = q[0]; B1 = q[1]; B2 = q[2]; B3 = q[3];
        GAUSS_REC4(A0, A1, A2, A3);
        q = sp + (size_t)(g + 2) * 4;
        A0 = q[0]; A1 = q[1]; A2 = q[2]; A3 = q[3];
        GAUSS_REC4(B0, B1, B2, B3);
    }
    __syncthreads();
    float* part = (float*)spbuf;
    part[w * 256 + 0 + lane] = acc0;
    part[w * 256 + 64 + lane] = acc1;
    part[w * 256 + 128 + lane] = acc2;
    part[w * 256 + 192 + lane] = acc3;
    __syncthreads();
    float y = part[tid] + part[256 + tid] + part[512 + tid] + part[768 + tid];
    int p = pg * 256 + tid;
    bool m = mode ? (((const uint8_t*)inside)[p] != 0)
                  : (((const int*)inside)[p] != 0);
    if (m) atomicAdd(&out[p], y);
}

extern "C" void kernel_launch(void* const* d_in, const int* in_sizes, int n_in,
                              void* d_out, int out_size, void* d_ws, size_t ws_size,
                              hipStream_t stream) {
    const float* x        = (const float*)d_in[0];
    const float* xyz      = (const float*)d_in[1];
    const float* weight   = (const float*)d_in[2];
    const float* scaling  = (const float*)d_in[3];
    const float* rotation = (const float*)d_in[4];
    const float* values   = (const float*)d_in[5];
    const void*  inside   = d_in[6];

    float* ws = (float*)d_ws;

    if (ws_size >= (size_t)NEED_FLOATS * 4) {
        precompute_kernel<<<(G_N + 255) / 256, 256, 0, stream>>>(
            xyz, weight, scaling, rotation, values, (const uint8_t*)inside, ws, 1);
        scatter_kernel<<<P_N / 256, 256, 0, stream>>>(x, ws);
        eval_cell_kernel<<<NCELL, 512, 0, stream>>>(ws, inside, (float*)d_out);
    } else if (ws_size >= (size_t)(256 + (G_N + 2) * 16 * 4)) {
        zero_out_kernel<<<P_N / 256, 256, 0, stream>>>((float*)d_out);
        precompute_kernel<<<(G_N + 255) / 256, 256, 0, stream>>>(
            xyz, weight, scaling, rotation, values, (const uint8_t*)inside, ws, 0);
        eval_kernel<<<(P_N / 256) * 8, 256, 0, stream>>>(
            x, ws, inside, (float*)d_out);
    }
}

// Round 11
// 25.927 us; speedup vs baseline: 4.0788x; 1.5572x over previous
//
#include <hip/hip_runtime.h>
#include <cstdint>

#define P_N 65536
#define G_N 2048
#define L2E 1.4426950408889634f
#define NCELL 512              // 8x8x8 grid
#define BCAP 320               // bucket capacity (mean 128, sd ~11)
#define CHUNK 256              // records staged per LDS chunk (covers ~all cells)
#define CNT_STRIDE 16          // one cacheline per cell counter (atomic spread)

#if __has_builtin(__builtin_amdgcn_exp2f)
#define EXP2F __builtin_amdgcn_exp2f
#else
#define EXP2F exp2f
#endif

// ---- ws layout (units: floats/ints, 4B each) ----
#define OFF_FLAG 0
#define OFF_PAR  64
#define OFF_MU   (OFF_PAR + (G_N + 2) * 16)       // float4 (mu.xyz, r2)
#define OFF_CNT  (OFF_MU + G_N * 4)               // 512 counters, stride 16
#define OFF_BKT  (OFF_CNT + NCELL * CNT_STRIDE)   // 512*BCAP float4 (X,Y,Z,idx)
#define NEED_FLOATS (OFF_BKT + NCELL * BCAP * 4)  // ~2.82 MB

__device__ __forceinline__ float sigmoidf(float x) {
    return 1.0f / (1.0f + expf(-x));
}

// params: [0..8] M = sqrt(L2E/2)*diag(1/s)*R^T, [9..11] nb=-M·mu, [12] lw, pad
__global__ __launch_bounds__(256) void precompute_kernel(
        const float* __restrict__ xyz,
        const float* __restrict__ weight,
        const float* __restrict__ scaling,
        const float* __restrict__ rotation,
        const float* __restrict__ values,
        const uint8_t* __restrict__ inside_raw,
        float* __restrict__ ws, int aux) {
    // zero padded cell counters (all 8 blocks participate; scatter runs later)
    if (aux) {
        for (int i = blockIdx.x * 256 + threadIdx.x; i < NCELL * CNT_STRIDE;
             i += 2048)
            ((int*)ws)[OFF_CNT + i] = 0;
    }
    if (blockIdx.x == 0) {
        __shared__ int s_nz;
        if (threadIdx.x == 0) s_nz = 0;
        __syncthreads();
        int nz = 0;
        for (int i = threadIdx.x; i < 4096; i += blockDim.x) {
            if ((i & 3) != 0 && inside_raw[i] != 0) nz = 1;
        }
        if (nz) atomicOr(&s_nz, 1);
        __syncthreads();
        if (threadIdx.x == 0) ((int*)ws)[OFF_FLAG] = s_nz;
        if (threadIdx.x < 32) ws[OFF_PAR + (size_t)G_N * 16 + threadIdx.x] = 0.0f;
    }

    int g = blockIdx.x * blockDim.x + threadIdx.x;
    if (g >= G_N) return;

    float s0 = expf(scaling[3 * g + 0]);
    float s1 = expf(scaling[3 * g + 1]);
    float s2 = expf(scaling[3 * g + 2]);
    float r = sqrtf(s0 * s0 + s1 * s1 + s2 * s2) + 1e-8f;
    float r_soft = 0.02f * tanhf(r / 0.02f);
    float f = r_soft / r;
    s0 *= f; s1 *= f; s2 *= f;

    float qw = rotation[4 * g + 0], qx = rotation[4 * g + 1];
    float qy = rotation[4 * g + 2], qz = rotation[4 * g + 3];
    float qn = sqrtf(qw * qw + qx * qx + qy * qy + qz * qz) + 1e-12f;
    qw /= qn; qx /= qn; qy /= qn; qz /= qn;
    float r00 = 1.0f - 2.0f * (qy * qy + qz * qz);
    float r01 = 2.0f * (qx * qy - qw * qz);
    float r02 = 2.0f * (qx * qz + qw * qy);
    float r10 = 2.0f * (qx * qy + qw * qz);
    float r11 = 1.0f - 2.0f * (qx * qx + qz * qz);
    float r12 = 2.0f * (qy * qz - qw * qx);
    float r20 = 2.0f * (qx * qz - qw * qy);
    float r21 = 2.0f * (qy * qz + qw * qx);
    float r22 = 1.0f - 2.0f * (qx * qx + qy * qy);

    const float k = 0.84932180028801904f;  // sqrt(L2E*0.5)
    float k0 = k / s0, k1 = k / s1, k2 = k / s2;
    float m00 = k0 * r00, m01 = k0 * r10, m02 = k0 * r20;
    float m10 = k1 * r01, m11 = k1 * r11, m12 = k1 * r21;
    float m20 = k2 * r02, m21 = k2 * r12, m22 = k2 * r22;

    float mx = xyz[3 * g + 0], my = xyz[3 * g + 1], mz = xyz[3 * g + 2];
    float wv = sigmoidf(weight[g]) * sigmoidf(values[g]);

    float* c = ws + OFF_PAR + (size_t)g * 16;
    c[0] = m00; c[1] = m01; c[2] = m02;
    c[3] = m10; c[4] = m11; c[5] = m12;
    c[6] = m20; c[7] = m21; c[8] = m22;
    c[9]  = -(m00 * mx + m01 * my + m02 * mz);
    c[10] = -(m10 * mx + m11 * my + m12 * mz);
    c[11] = -(m20 * mx + m21 * my + m22 * mz);
    c[12] = log2f(wv);
    c[13] = 0.0f; c[14] = 0.0f; c[15] = 0.0f;

    if (aux) {
        // keep iff dist2(mu, cellbox) < 40*smax^2  (term bound 2^-28.8)
        float smax = fmaxf(s0, fmaxf(s1, s2));
        ((float4*)(ws + OFF_MU))[g] = make_float4(mx, my, mz, 40.0f * smax * smax);
    }
}

__global__ __launch_bounds__(256) void scatter_kernel(
        const float* __restrict__ x, float* __restrict__ ws) {
    int p = blockIdx.x * 256 + threadIdx.x;
    float X = (x[3 * p + 0] + 1.0f) * 0.5f;
    float Y = (x[3 * p + 1] + 1.0f) * 0.5f;
    float Z = (x[3 * p + 2] + 1.0f) * 0.5f;
    int cx = min(7, max(0, (int)(X * 8.0f)));
    int cy = min(7, max(0, (int)(Y * 8.0f)));
    int cz = min(7, max(0, (int)(Z * 8.0f)));
    int c = cx + 8 * cy + 64 * cz;
    int pos = atomicAdd(&((int*)ws)[OFF_CNT + c * CNT_STRIDE], 1);
    if (pos < BCAP)
        ((float4*)(ws + OFF_BKT))[(size_t)c * BCAP + pos] =
            make_float4(X, Y, Z, __int_as_float(p));
}

// record applied to one point; record in float4 regs r0..r3
#define GPOINT(r0, r1, r2, r3, Xk, Yk, Zk, acck)                              \
    {                                                                         \
        float u0 = fmaf(r0.x, Xk, fmaf(r0.y, Yk, fmaf(r0.z, Zk, r2.y)));      \
        float u1 = fmaf(r0.w, Xk, fmaf(r1.x, Yk, fmaf(r1.y, Zk, r2.z)));      \
        float u2 = fmaf(r1.z, Xk, fmaf(r1.w, Yk, fmaf(r2.x, Zk, r2.w)));      \
        float tt = fmaf(-u0, u0, r3.x);                                       \
        tt = fmaf(-u1, u1, tt);                                               \
        tt = fmaf(-u2, u2, tt);                                               \
        acck += EXP2F(tt);                                                    \
    }

// one block per cell: ballot-compacted list -> staged records -> PT=2
// ping-pong inner loop (lane-group q = t&3 takes every 4th record)
__global__ __launch_bounds__(512) void eval_cell_kernel(
        const float* __restrict__ ws,
        const void* __restrict__ inside,
        float* __restrict__ out) {
    __shared__ int    slist[G_N];          // 8 KB
    __shared__ float4 sbuf[CHUNK * 4];     // 16 KB
    __shared__ float  comb[4][256];        // 4 KB
    __shared__ int    scnt;

    const int mode = ((const int*)ws)[OFF_FLAG];
    const int c = blockIdx.x;
    const int t = threadIdx.x;
    const int lane = t & 63;

    int npts = ((const int*)ws)[OFF_CNT + c * CNT_STRIDE];
    npts = min(npts, BCAP);
    if (npts == 0) return;

    const int cx = c & 7, cy = (c >> 3) & 7, cz = c >> 6;
    const float bnx = cx * 0.125f, bxx = bnx + 0.125f;
    const float bny = cy * 0.125f, bxy = bny + 0.125f;
    const float bnz = cz * 0.125f, bxz = bnz + 0.125f;

    if (t == 0) scnt = 0;
    __syncthreads();

    // ballot-compacted active list (1 LDS atomic per wave per round)
    const float4* mu4 = (const float4*)(ws + OFF_MU);
    const unsigned long long lmask =
        (lane == 63) ? ~0ull : ((1ull << (lane + 1)) - 1ull);
#pragma unroll
    for (int i = 0; i < G_N / 512; ++i) {
        int g = t + 512 * i;
        float4 m = mu4[g];
        float dx = fmaxf(fmaxf(bnx - m.x, m.x - bxx), 0.0f);
        float dy = fmaxf(fmaxf(bny - m.y, m.y - bxy), 0.0f);
        float dz = fmaxf(fmaxf(bnz - m.z, m.z - bxz), 0.0f);
        float d2 = dx * dx + dy * dy + dz * dz;
        bool keep = d2 < m.w;
        unsigned long long mask = __ballot(keep);
        int nk = __popcll(mask);
        int pref = __popcll(mask & lmask) - (keep ? 1 : 0);
        int base = 0;
        if (lane == 0) base = atomicAdd(&scnt, nk);
        base = __shfl(base, 0);
        if (keep) slist[base + pref] = g;
    }
    __syncthreads();
    const int cnt = scnt;
    const float4* par4 = (const float4*)(ws + OFF_PAR);
    const float4* bkt  = (const float4*)(ws + OFF_BKT) + (size_t)c * BCAP;

    const int q    = t & 3;    // record lane-group (every 4th record)
    const int pair = t >> 2;   // 0..127 -> 2 adjacent points

    for (int pbase = 0; pbase < npts; pbase += 256) {
        __syncthreads();       // comb reuse guard across batches
        int lp0 = 2 * pair, lp1 = lp0 + 1;
        int gp0 = pbase + lp0, gp1 = pbase + lp1;
        bool v0 = gp0 < npts, v1 = gp1 < npts;
        float4 ptA = bkt[v0 ? gp0 : 0];
        float4 ptB = bkt[v1 ? gp1 : 0];
        float X0 = ptA.x, Y0 = ptA.y, Z0 = ptA.z;
        float X1 = ptB.x, Y1 = ptB.y, Z1 = ptB.z;
        float a0 = 0.0f, a1 = 0.0f;

        for (int c0 = 0; c0 < cnt; c0 += CHUNK) {
            int cn = min(CHUNK, cnt - c0);
            __syncthreads();
            for (int idx = t; idx < cn * 4; idx += 512) {
                int g = slist[c0 + (idx >> 2)];
                sbuf[idx] = par4[(size_t)g * 4 + (idx & 3)];
            }
            __syncthreads();
            if (v0) {          // whole-wave skip when point range invalid
                int ia = min(q, cn - 1);
                float4 A0 = sbuf[ia * 4 + 0], A1 = sbuf[ia * 4 + 1];
                float4 A2 = sbuf[ia * 4 + 2], A3 = sbuf[ia * 4 + 3];
#pragma unroll 1
                for (int j = q; j < cn; j += 4) {
                    int ib = min(j + 4, cn - 1);   // clamped prefetch
                    float4 B0 = sbuf[ib * 4 + 0], B1 = sbuf[ib * 4 + 1];
                    float4 B2 = sbuf[ib * 4 + 2], B3 = sbuf[ib * 4 + 3];
                    GPOINT(A0, A1, A2, A3, X0, Y0, Z0, a0);
                    GPOINT(A0, A1, A2, A3, X1, Y1, Z1, a1);
                    A0 = B0; A1 = B1; A2 = B2; A3 = B3;
                }
            }
        }

        __syncthreads();
        comb[q][lp0] = v0 ? a0 : 0.0f;
        comb[q][lp1] = v1 ? a1 : 0.0f;
        __syncthreads();
        if (t < 256) {
            int gp = pbase + t;
            if (gp < npts) {
                float y = comb[0][t] + comb[1][t] + comb[2][t] + comb[3][t];
                float4 pt = bkt[gp];
                int p = __float_as_int(pt.w);
                bool m = mode ? (((const uint8_t*)inside)[p] != 0)
                              : (((const int*)inside)[p] != 0);
                out[p] = m ? y : 0.0f;   // every point stored exactly once
            }
        }
    }
}

// ---------- fallback for small ws (round-6 path) ----------
__global__ __launch_bounds__(256) void zero_out_kernel(float* __restrict__ out) {
    out[blockIdx.x * 256 + threadIdx.x] = 0.0f;
}

#define GAUSS_REC4(r0, r1, r2, r3)                                            \
    GPOINT(r0, r1, r2, r3, X0, Y0, Z0, acc0);                                 \
    GPOINT(r0, r1, r2, r3, X1, Y1, Z1, acc1);                                 \
    GPOINT(r0, r1, r2, r3, X2, Y2, Z2, acc2);                                 \
    GPOINT(r0, r1, r2, r3, X3, Y3, Z3, acc3);

__global__ __launch_bounds__(256) void eval_kernel(
        const float* __restrict__ x,
        const float* __restrict__ ws,
        const void* __restrict__ inside,
        float* __restrict__ out) {
    __shared__ float4 spbuf[1028];
    const float* params = ws + OFF_PAR;
    const int mode = ((const int*)ws)[OFF_FLAG];
    const int tid = threadIdx.x, lane = tid & 63, w = tid >> 6;
    const int segq = blockIdx.x & 7, pg = blockIdx.x >> 3;

    const float4* src = (const float4*)(params + (size_t)segq * 256 * 16);
#pragma unroll
    for (int i = 0; i < 4; ++i) spbuf[tid + 256 * i] = src[tid + 256 * i];
    if (tid < 4) spbuf[1024 + tid] = src[1024 + tid];

    const int p0 = pg * 256 + lane;
    float X0 = (x[3 * (p0 + 0) + 0] + 1.0f) * 0.5f;
    float Y0 = (x[3 * (p0 + 0) + 1] + 1.0f) * 0.5f;
    float Z0 = (x[3 * (p0 + 0) + 2] + 1.0f) * 0.5f;
    float X1 = (x[3 * (p0 + 64) + 0] + 1.0f) * 0.5f;
    float Y1 = (x[3 * (p0 + 64) + 1] + 1.0f) * 0.5f;
    float Z1 = (x[3 * (p0 + 64) + 2] + 1.0f) * 0.5f;
    float X2 = (x[3 * (p0 + 128) + 0] + 1.0f) * 0.5f;
    float Y2 = (x[3 * (p0 + 128) + 1] + 1.0f) * 0.5f;
    float Z2 = (x[3 * (p0 + 128) + 2] + 1.0f) * 0.5f;
    float X3 = (x[3 * (p0 + 192) + 0] + 1.0f) * 0.5f;
    float Y3 = (x[3 * (p0 + 192) + 1] + 1.0f) * 0.5f;
    float Z3 = (x[3 * (p0 + 192) + 2] + 1.0f) * 0.5f;
    __syncthreads();

    const float4* sp = spbuf + (size_t)w * 256;
    float acc0 = 0, acc1 = 0, acc2 = 0, acc3 = 0;
    float4 A0 = sp[0], A1 = sp[1], A2 = sp[2], A3 = sp[3];
    float4 B0, B1, B2, B3;
#pragma unroll 1
    for (int g = 0; g < 64; g += 2) {
        const float4* qq = sp + (size_t)(g + 1) * 4;
        B0 = qq[0]; B1 = qq[1]; B2 = qq[2]; B3 = qq[3];
        GAUSS_REC4(A0, A1, A2, A3);
        qq = sp + (size_t)(g + 2) * 4;
        A0 = qq[0]; A1 = qq[1]; A2 = qq[2]; A3 = qq[3];
        GAUSS_REC4(B0, B1, B2, B3);
    }
    __syncthreads();
    float* part = (float*)spbuf;
    part[w * 256 + 0 + lane] = acc0;
    part[w * 256 + 64 + lane] = acc1;
    part[w * 256 + 128 + lane] = acc2;
    part[w * 256 + 192 + lane] = acc3;
    __syncthreads();
    float y = part[tid] + part[256 + tid] + part[512 + tid] + part[768 + tid];
    int p = pg * 256 + tid;
    bool m = mode ? (((const uint8_t*)inside)[p] != 0)
                  : (((const int*)inside)[p] != 0);
    if (m) atomicAdd(&out[p], y);
}

extern "C" void kernel_launch(void* const* d_in, const int* in_sizes, int n_in,
                              void* d_out, int out_size, void* d_ws, size_t ws_size,
                              hipStream_t stream) {
    const float* x        = (const float*)d_in[0];
    const float* xyz      = (const float*)d_in[1];
    const float* weight   = (const float*)d_in[2];
    const float* scaling  = (const float*)d_in[3];
    const float* rotation = (const float*)d_in[4];
    const float* values   = (const float*)d_in[5];
    const void*  inside   = d_in[6];

    float* ws = (float*)d_ws;

    if (ws_size >= (size_t)NEED_FLOATS * 4) {
        precompute_kernel<<<(G_N + 255) / 256, 256, 0, stream>>>(
            xyz, weight, scaling, rotation, values, (const uint8_t*)inside, ws, 1);
        scatter_kernel<<<P_N / 256, 256, 0, stream>>>(x, ws);
        eval_cell_kernel<<<NCELL, 512, 0, stream>>>(ws, inside, (float*)d_out);
    } else if (ws_size >= (size_t)(256 + (G_N + 2) * 16 * 4)) {
        zero_out_kernel<<<P_N / 256, 256, 0, stream>>>((float*)d_out);
        precompute_kernel<<<(G_N + 255) / 256, 256, 0, stream>>>(
            xyz, weight, scaling, rotation, values, (const uint8_t*)inside, ws, 0);
        eval_kernel<<<(P_N / 256) * 8, 256, 0, stream>>>(
            x, ws, inside, (float*)d_out);
    }
}